// Round 7
// baseline (161.263 us; speedup 1.0000x reference)
//
#include <hip/hip_runtime.h>
#include <math.h>

typedef __attribute__((ext_vector_type(8))) short short8;
typedef __attribute__((ext_vector_type(4))) float f32x4;
typedef unsigned short ushort_t;

#define TSEQ   4096
#define NBATCH 4
#define DMODEL 768
#define HS     64
#define KSPLIT 4

static __device__ __forceinline__ ushort_t f2bf(float f) {
  union { float f; unsigned u; } v; v.f = f;
  unsigned r = v.u + 0x7fffu + ((v.u >> 16) & 1u);   // RNE
  return (ushort_t)(r >> 16);
}
static __device__ __forceinline__ float bf2f(ushort_t u) {
  union { unsigned u; float f; } v; v.u = ((unsigned)u) << 16; return v.f;
}

#define MFMA16(a,b,c) __builtin_amdgcn_mfma_f32_16x16x32_bf16((a),(b),(c),0,0,0)

// ---------------- W prep (coalesced LDS transpose) ----------------
__global__ __launch_bounds__(256) void wprep(
    const float* __restrict__ Wq, const float* __restrict__ Wk,
    const float* __restrict__ Wv, ushort_t* __restrict__ Wt)
{
  __shared__ float lds[64 * 65];
  const int m = blockIdx.x / 12, kc = blockIdx.x % 12, k0 = kc * 64;
  const float* W = (m == 0) ? Wq : (m == 1) ? Wk : Wv;
  const int tid = threadIdx.x;
#pragma unroll
  for (int i = 0; i < 16; i++) {
    const int row = i * 4 + (tid >> 6), col = tid & 63;
    lds[row * 65 + col] = W[(size_t)(k0 + row) * HS + col];   // coalesced
  }
  __syncthreads();
#pragma unroll
  for (int i = 0; i < 16; i++) {
    const int n = i * 4 + (tid >> 6), kk = tid & 63;
    Wt[(size_t)(m * 64 + n) * DMODEL + k0 + kk] = f2bf(lds[kk * 65 + n]);
  }
}

// ---------------- QKV projection v4: wave-autonomous, barrier-free ----------
// 2048 waves = 512 blocks x 256 thr. Wave gw: rows (gw>>1)*16..+15, n-half
// gw&1 (96 cols). A read direct-from-global in frag layout; B from L2-resident
// Wt. Depth-4 register rings for A and B -> loads issued 4 chunks before use,
// no barriers so nothing forces vmcnt(0) (round-6 fix: barrier drains killed
// every previous prefetch, compiler sank loads, VGPR=64).
__global__ __launch_bounds__(256, 2) void qkv_mfma(
    const float* __restrict__ x, const ushort_t* __restrict__ Wt,
    ushort_t* __restrict__ q, ushort_t* __restrict__ kO, ushort_t* __restrict__ vT)
{
  __shared__ __align__(16) float vls[4][16 * 68];   // wave-private v-transpose

  const int tid  = threadIdx.x;
  const int w    = tid >> 6, lane = tid & 63;
  const int l16  = lane & 15, quad = lane >> 4;
  const int gw   = blockIdx.x * 4 + w;              // 0..2047
  const int R0   = (gw >> 1) * 16;
  const int nHalf = gw & 1;

  const float* xr = x + (size_t)(R0 + l16) * DMODEL + quad * 8;
  const ushort_t* wb = Wt + (size_t)(nHalf * 96 + l16) * DMODEL + quad * 8;

  f32x4 acc[6];
#pragma unroll
  for (int nt = 0; nt < 6; nt++) acc[nt] = (f32x4){0.f, 0.f, 0.f, 0.f};

  float4 ar[4][2];                                  // A ring, depth 4
  short8 br[4][6];                                  // B ring, depth 4
#pragma unroll
  for (int j = 0; j < 4; j++) {
    ar[j][0] = *(const float4*)(xr + j * 32);
    ar[j][1] = *(const float4*)(xr + j * 32 + 4);
#pragma unroll
    for (int nt = 0; nt < 6; nt++)
      br[j][nt] = *(const short8*)(wb + (size_t)nt * 16 * DMODEL + j * 32);
  }

  for (int mi = 0; mi < 6; mi++) {                  // 24 chunks of K=32
#pragma unroll
    for (int j = 0; j < 4; j++) {
      short8 af;
      af[0]=f2bf(ar[j][0].x); af[1]=f2bf(ar[j][0].y);
      af[2]=f2bf(ar[j][0].z); af[3]=f2bf(ar[j][0].w);
      af[4]=f2bf(ar[j][1].x); af[5]=f2bf(ar[j][1].y);
      af[6]=f2bf(ar[j][1].z); af[7]=f2bf(ar[j][1].w);
#pragma unroll
      for (int nt = 0; nt < 6; nt++) acc[nt] = MFMA16(af, br[j][nt], acc[nt]);
      const int kn = mi * 4 + j + 4;                // reload ring slot, dist 4
      if (kn < 24) {
        ar[j][0] = *(const float4*)(xr + kn * 32);
        ar[j][1] = *(const float4*)(xr + kn * 32 + 4);
#pragma unroll
        for (int nt = 0; nt < 6; nt++)
          br[j][nt] = *(const short8*)(wb + (size_t)nt * 16 * DMODEL + kn * 32);
      }
    }
  }

  // ---- epilogue: q/k direct stores; v via wave-private LDS transpose ----
#pragma unroll
  for (int nt = 0; nt < 6; nt++) {
    const int gnt = nHalf * 6 + nt;
    const int mat = gnt >> 2;                       // 0=q 1=k 2=v (wave-uniform)
    const int col = (gnt & 3) * 16 + l16;
#pragma unroll
    for (int r = 0; r < 4; r++) {
      const float val = acc[nt][r];
      const int trow = R0 + quad * 4 + r;
      if (mat == 0)      q [(size_t)trow * HS + col] = f2bf(val * 0.125f);
      else if (mat == 1) kO[(size_t)trow * HS + col] = f2bf(val);
      else               vls[w][(quad * 4 + r) * 68 + col] = val;
    }
  }
  if (nHalf == 1) {                                 // v cols live in this wave
    const int d = lane;                             // in-wave LDS RAW: compiler
    short8 p0, p1;                                  // inserts lgkmcnt waits
#pragma unroll
    for (int i = 0; i < 8; i++) p0[i] = (short)f2bf(vls[w][i * 68 + d]);
#pragma unroll
    for (int i = 0; i < 8; i++) p1[i] = (short)f2bf(vls[w][(8 + i) * 68 + d]);
    ushort_t* dst = vT + ((size_t)(R0 >> 12) * HS + d) * TSEQ + (R0 & (TSEQ - 1));
    *(short8*)(dst)     = p0;
    *(short8*)(dst + 8) = p1;
  }
}

// ---------------- attention pass 1: partial flash attention ----------------
// grid = 128 jt x B x KSPLIT(4) = 2048 blocks, 128 thr (2 waves). Loop order
// fixed (round-6): prefetch -> compute -> barrier -> write -> barrier, so the
// global loads fly during the whole MFMA+softmax phase.
#define KP 72
__global__ __launch_bounds__(128) void attn_part(
    const ushort_t* __restrict__ q, const ushort_t* __restrict__ k,
    const ushort_t* __restrict__ vT, float* __restrict__ ML, ushort_t* __restrict__ OP)
{
  __shared__ __align__(16) ushort_t sK[64 * KP];     // [key][d]
  __shared__ __align__(16) ushort_t sV[64 * KP];     // [d][key]
  __shared__ __align__(16) ushort_t sP[2][16 * KP];  // per-wave P

  const int idx  = blockIdx.x;
  const int s    = idx & 3;
  const int b    = (idx >> 2) & 3;
  const int jt   = 127 - (idx >> 4);           // descending work order
  const int tid  = threadIdx.x;
  const int w    = tid >> 6;
  const int lane = tid & 63;
  const int l16  = lane & 15, quad = lane >> 4;
  const int R0   = jt * 32 + w * 16;

  const ushort_t* qg = q  + (size_t)b * TSEQ * HS;
  const ushort_t* kg = k  + (size_t)b * TSEQ * HS;
  const ushort_t* vg = vT + (size_t)b * HS * TSEQ;

  const short8 qf0 = *(const short8*)(qg + (R0 + l16) * HS +      quad * 8);
  const short8 qf1 = *(const short8*)(qg + (R0 + l16) * HS + 32 + quad * 8);

  f32x4 o[4];
#pragma unroll
  for (int dt = 0; dt < 4; dt++) o[dt] = (f32x4){0.f, 0.f, 0.f, 0.f};
  float mrow = -INFINITY, lrow = 0.f;          // per-lane qrow = R0 + l16

  const int nkt = jt / 2 + 1;                  // 64-key chunks incl. diagonal
  if (s < nkt) {
    {                                          // initial stage of chunk s
      const int k0 = s * 64;
      short8 kpre[4], vpre[4];
#pragma unroll
      for (int i = 0; i < 4; i++) {
        const int c = i * 128 + tid, key = c >> 3, ch = c & 7;
        kpre[i] = *(const short8*)(kg + (size_t)(k0 + key) * HS + ch * 8);
        vpre[i] = *(const short8*)(vg + (size_t)key * TSEQ + k0 + ch * 8);
      }
#pragma unroll
      for (int i = 0; i < 4; i++) {
        const int c = i * 128 + tid, key = c >> 3, ch = c & 7;
        *(short8*)(sK + key * KP + ch * 8) = kpre[i];
        *(short8*)(sV + key * KP + ch * 8) = vpre[i];
      }
      __syncthreads();
    }
    for (int kt = s; kt < nkt; kt += KSPLIT) {
      const int k0 = kt * 64;
      const int kn = kt + KSPLIT;
      short8 kpre[4], vpre[4];
      if (kn < nkt) {                          // issue BEFORE compute
        const int g0 = kn * 64;
#pragma unroll
        for (int i = 0; i < 4; i++) {
          const int c = i * 128 + tid, key = c >> 3, ch = c & 7;
          kpre[i] = *(const short8*)(kg + (size_t)(g0 + key) * HS + ch * 8);
          vpre[i] = *(const short8*)(vg + (size_t)key * TSEQ + g0 + ch * 8);
        }
      }
      // ---- S^T = K Q^T : C[key = ct*16+quad*4+r][qrow = l16] ----
      f32x4 sT[4];
#pragma unroll
      for (int ct = 0; ct < 4; ct++) {
        sT[ct] = (f32x4){0.f, 0.f, 0.f, 0.f};
        const short8 kfa = *(const short8*)(sK + (ct * 16 + l16) * KP +      quad * 8);
        const short8 kfb = *(const short8*)(sK + (ct * 16 + l16) * KP + 32 + quad * 8);
        sT[ct] = MFMA16(kfa, qf0, sT[ct]);
        sT[ct] = MFMA16(kfb, qf1, sT[ct]);
      }
      if (k0 + 63 > R0) {                      // causal mask, diagonal only
        const int qrow = R0 + l16;
#pragma unroll
        for (int ct = 0; ct < 4; ct++)
#pragma unroll
          for (int r = 0; r < 4; r++)
            sT[ct][r] = (k0 + ct * 16 + quad * 4 + r <= qrow) ? sT[ct][r] : -INFINITY;
      }
      // ---- online softmax (per-lane row; 2 cross-quad shuffles) ----
      float tm = -INFINITY;
#pragma unroll
      for (int ct = 0; ct < 4; ct++)
#pragma unroll
        for (int r = 0; r < 4; r++) tm = fmaxf(tm, sT[ct][r]);
      tm = fmaxf(tm, __shfl_xor(tm, 16));
      tm = fmaxf(tm, __shfl_xor(tm, 32));
      const float mn = fmaxf(mrow, tm);
      const float al = __expf(mrow - mn);
      mrow = mn;
      float ps = 0.f;
#pragma unroll
      for (int ct = 0; ct < 4; ct++)
#pragma unroll
        for (int r = 0; r < 4; r++) { sT[ct][r] = __expf(sT[ct][r] - mn); ps += sT[ct][r]; }
      ps += __shfl_xor(ps, 16);
      ps += __shfl_xor(ps, 32);
      lrow = lrow * al + ps;
      // ---- P -> LDS (A-layout), O rescale, PV ----
      ushort_t* Pw = &sP[w][0];
#pragma unroll
      for (int ct = 0; ct < 4; ct++) {
        ushort4 pk;
        pk.x = f2bf(sT[ct][0]); pk.y = f2bf(sT[ct][1]);
        pk.z = f2bf(sT[ct][2]); pk.w = f2bf(sT[ct][3]);
        *(ushort4*)(Pw + l16 * KP + ct * 16 + quad * 4) = pk;
      }
      float alo[4];
#pragma unroll
      for (int r = 0; r < 4; r++) alo[r] = __shfl(al, quad * 4 + r);
#pragma unroll
      for (int dt = 0; dt < 4; dt++)
#pragma unroll
        for (int r = 0; r < 4; r++) o[dt][r] *= alo[r];
      const short8 pf0 = *(const short8*)(Pw + l16 * KP +      quad * 8);
      const short8 pf1 = *(const short8*)(Pw + l16 * KP + 32 + quad * 8);
#pragma unroll
      for (int dt = 0; dt < 4; dt++) {
        const short8 vfa = *(const short8*)(sV + (dt * 16 + l16) * KP +      quad * 8);
        const short8 vfb = *(const short8*)(sV + (dt * 16 + l16) * KP + 32 + quad * 8);
        o[dt] = MFMA16(pf0, vfa, o[dt]);
        o[dt] = MFMA16(pf1, vfb, o[dt]);
      }
      if (kn < nkt) {                          // rotate staged tile
        __syncthreads();                       // all reads of current tile done
#pragma unroll
        for (int i = 0; i < 4; i++) {
          const int c = i * 128 + tid, key = c >> 3, ch = c & 7;
          *(short8*)(sK + key * KP + ch * 8) = kpre[i];
          *(short8*)(sV + key * KP + ch * 8) = vpre[i];
        }
        __syncthreads();                       // new tile visible
      }
    }
  }

  // ---- write partials: ML fp32 [B][KSPLIT][T][2], OP bf16 [B][KSPLIT][T][64] ----
  const size_t base = ((size_t)(b * KSPLIT + s) * TSEQ);
  if (quad == 0) {
    ML[(base + R0 + l16) * 2 + 0] = mrow;
    ML[(base + R0 + l16) * 2 + 1] = lrow;
  }
#pragma unroll
  for (int dt = 0; dt < 4; dt++)
#pragma unroll
    for (int r = 0; r < 4; r++)
      OP[(base + R0 + quad * 4 + r) * HS + dt * 16 + l16] = f2bf(o[dt][r]);
}

// ---------------- attention pass 2: merge the KSPLIT partials ----------------
__global__ __launch_bounds__(256) void attn_merge(
    const float* __restrict__ ML, const ushort_t* __restrict__ OP,
    float* __restrict__ out)
{
  const int row = blockIdx.x * 16 + (threadIdx.x >> 4);   // 0..16383
  const int b   = row >> 12, t = row & (TSEQ - 1);
  const int d0  = (threadIdx.x & 15) * 4;
  float m[KSPLIT], l[KSPLIT];
  float M = -INFINITY;
#pragma unroll
  for (int ss = 0; ss < KSPLIT; ss++) {
    const size_t i = ((size_t)(b * KSPLIT + ss) * TSEQ + t);
    m[ss] = ML[i * 2]; l[ss] = ML[i * 2 + 1];
    M = fmaxf(M, m[ss]);
  }
  float den = 0.f;
  float4 num = make_float4(0.f, 0.f, 0.f, 0.f);
#pragma unroll
  for (int ss = 0; ss < KSPLIT; ss++) {
    const float a = __expf(m[ss] - M);          // zero-trip split: weight 0
    den += l[ss] * a;
    const size_t i = ((size_t)(b * KSPLIT + ss) * TSEQ + t);
    const ushort4 u = *(const ushort4*)(OP + i * HS + d0);
    num.x += a * bf2f(u.x); num.y += a * bf2f(u.y);
    num.z += a * bf2f(u.z); num.w += a * bf2f(u.w);
  }
  const float inv = 1.f / den;
  *(float4*)(out + (size_t)row * HS + d0) =
      make_float4(num.x * inv, num.y * inv, num.z * inv, num.w * inv);
}

extern "C" void kernel_launch(void* const* d_in, const int* in_sizes, int n_in,
                              void* d_out, int out_size, void* d_ws, size_t ws_size,
                              hipStream_t stream) {
  const float* x  = (const float*)d_in[0];
  const float* Wq = (const float*)d_in[1];
  const float* Wk = (const float*)d_in[2];
  const float* Wv = (const float*)d_in[3];
  float* out = (float*)d_out;

  // ws: Wt 288K | q 2M | k 2M | vT 2M | ML 512K | OP 8M
  char* ws = (char*)d_ws;
  ushort_t* Wt = (ushort_t*)ws;
  ushort_t* qb = (ushort_t*)(ws + 294912);
  ushort_t* kb = (ushort_t*)(ws + 294912 + 2097152);
  ushort_t* vb = (ushort_t*)(ws + 294912 + 2 * 2097152);
  float*    ml = (float*)   (ws + 294912 + 3 * 2097152);
  ushort_t* op = (ushort_t*)(ws + 294912 + 3 * 2097152 + 524288);

  wprep<<<36, 256, 0, stream>>>(Wq, Wk, Wv, Wt);
  qkv_mfma<<<512, 256, 0, stream>>>(x, Wt, qb, kb, vb);
  attn_part<<<128 * NBATCH * KSPLIT, 128, 0, stream>>>(qb, kb, vb, ml, op);
  attn_merge<<<1024, 256, 0, stream>>>(ml, op, out);
}

// Round 8
// 160.462 us; speedup vs baseline: 1.0050x; 1.0050x over previous
//
#include <hip/hip_runtime.h>
#include <math.h>

typedef __attribute__((ext_vector_type(8))) short short8;
typedef __attribute__((ext_vector_type(4))) float f32x4;
typedef unsigned short ushort_t;

#define TSEQ   4096
#define NBATCH 4
#define DMODEL 768
#define HS     64
#define KSPLIT 4

static __device__ __forceinline__ ushort_t f2bf(float f) {
  union { float f; unsigned u; } v; v.f = f;
  unsigned r = v.u + 0x7fffu + ((v.u >> 16) & 1u);   // RNE
  return (ushort_t)(r >> 16);
}
static __device__ __forceinline__ float bf2f(ushort_t u) {
  union { unsigned u; float f; } v; v.u = ((unsigned)u) << 16; return v.f;
}

#define MFMA16(a,b,c) __builtin_amdgcn_mfma_f32_16x16x32_bf16((a),(b),(c),0,0,0)

// async global->LDS DMA, 16 B per lane; dest is wave-uniform base + lane*16
static __device__ __forceinline__ void gld16(ushort_t* lds, const ushort_t* g) {
  __builtin_amdgcn_global_load_lds(
      (const __attribute__((address_space(1))) unsigned int*)g,
      (__attribute__((address_space(3))) unsigned int*)lds, 16, 0, 0);
}

// ---------------- W prep (coalesced LDS transpose) ----------------
__global__ __launch_bounds__(256) void wprep(
    const float* __restrict__ Wq, const float* __restrict__ Wk,
    const float* __restrict__ Wv, ushort_t* __restrict__ Wt)
{
  __shared__ float lds[64 * 65];
  const int m = blockIdx.x / 12, kc = blockIdx.x % 12, k0 = kc * 64;
  const float* W = (m == 0) ? Wq : (m == 1) ? Wk : Wv;
  const int tid = threadIdx.x;
#pragma unroll
  for (int i = 0; i < 16; i++) {
    const int row = i * 4 + (tid >> 6), col = tid & 63;
    lds[row * 65 + col] = W[(size_t)(k0 + row) * HS + col];   // coalesced
  }
  __syncthreads();
#pragma unroll
  for (int i = 0; i < 16; i++) {
    const int n = i * 4 + (tid >> 6), kk = tid & 63;
    Wt[(size_t)(m * 64 + n) * DMODEL + k0 + kk] = f2bf(lds[kk * 65 + n]);
  }
}

// ---------------- x cast: fp32 -> bf16, pure streaming ----------------
// 16384*768 = 12.58M elems; 262144 threads x 6 iters x 8 elems.
__global__ __launch_bounds__(256) void xcast(
    const float* __restrict__ x, ushort_t* __restrict__ xb)
{
  const size_t i0 = ((size_t)blockIdx.x * 256 + threadIdx.x) * 8;
  const size_t stride = (size_t)262144 * 8;
#pragma unroll
  for (int it = 0; it < 6; it++) {
    const size_t e = i0 + (size_t)it * stride;
    const float4 a = *(const float4*)(x + e);
    const float4 b = *(const float4*)(x + e + 4);
    short8 p;
    p[0]=f2bf(a.x); p[1]=f2bf(a.y); p[2]=f2bf(a.z); p[3]=f2bf(a.w);
    p[4]=f2bf(b.x); p[5]=f2bf(b.y); p[6]=f2bf(b.z); p[7]=f2bf(b.w);
    *(short8*)(xb + e) = p;
  }
}

// ---------------- QKV projection v5: DMA-staged A, dbuf ----------------
// grid 512 = 256 M-tiles(64 rows) x 2 N-halves(96 cols); 256 thr / 4 waves;
// wave w owns rows w*16..+15, all 6 n-tiles of its half. A-tile staged via
// global_load_lds (no VGPR dest -> compiler can't sink it; issued right after
// the barrier so it flies across the whole compute phase). XOR-swizzled LDS
// (swizzle on DMA *source* addr; dest mapping is fixed) -> frag ds_reads are
// 2-way/bank = free. B-frags batch-loaded from L2-resident Wt each iter.
__global__ __launch_bounds__(256, 4) void qkv_mfma(
    const ushort_t* __restrict__ xb, const ushort_t* __restrict__ Wt,
    ushort_t* __restrict__ q, ushort_t* __restrict__ kO, ushort_t* __restrict__ vT)
{
  __shared__ __align__(16) ushort_t pool[2][64 * 64];   // A dbuf 16 KB; epilogue vls alias

  const int tid  = threadIdx.x;
  const int w    = tid >> 6, lane = tid & 63;
  const int l16  = lane & 15, quad = lane >> 4;
  const int M0   = (blockIdx.x >> 1) * 64;
  const int nHalf = blockIdx.x & 1;

  // DMA source mapping: LDS unit U holds global unit (row=U>>3, j=(U&7)^(row&7))
  const int U0 = (w * 2) * 64 + lane;
  const int U1 = (w * 2 + 1) * 64 + lane;
  const int r0 = U0 >> 3, j0 = (U0 & 7) ^ (r0 & 7);
  const int r1 = U1 >> 3, j1 = (U1 & 7) ^ (r1 & 7);
  const ushort_t* g0 = xb + (size_t)(M0 + r0) * DMODEL + j0 * 8;
  const ushort_t* g1 = xb + (size_t)(M0 + r1) * DMODEL + j1 * 8;

  const ushort_t* wb = Wt + (size_t)(nHalf * 96 + l16) * DMODEL + quad * 8;

  f32x4 acc[6];
#pragma unroll
  for (int nt = 0; nt < 6; nt++) acc[nt] = (f32x4){0.f, 0.f, 0.f, 0.f};

  gld16(&pool[0][U0 * 8], g0);                  // preload chunk 0
  gld16(&pool[0][U1 * 8], g1);

  for (int ks = 0; ks < 12; ks++) {
    __syncthreads();                            // DMA(ks) drained; old reads done
    if (ks < 11) {                              // DMA(ks+1): in flight all compute
      const int p = (ks + 1) & 1;
      gld16(&pool[p][U0 * 8], g0 + (ks + 1) * 64);
      gld16(&pool[p][U1 * 8], g1 + (ks + 1) * 64);
    }
    short8 bfr[12];                             // batch B loads (L2-resident)
#pragma unroll
    for (int nt = 0; nt < 6; nt++)
#pragma unroll
      for (int kc = 0; kc < 2; kc++)
        bfr[nt * 2 + kc] =
            *(const short8*)(wb + (size_t)nt * 16 * DMODEL + ks * 64 + kc * 32);
    const ushort_t* Ab = &pool[ks & 1][0];
    const int rl = w * 16 + l16;
#pragma unroll
    for (int kc = 0; kc < 2; kc++) {
      const int su = rl * 8 + ((kc * 4 + quad) ^ (rl & 7));
      const short8 af = *(const short8*)(Ab + su * 8);
#pragma unroll
      for (int nt = 0; nt < 6; nt++) acc[nt] = MFMA16(af, bfr[nt * 2 + kc], acc[nt]);
    }
  }

  // ---- epilogue: q/k direct stores ----
#pragma unroll
  for (int nt = 0; nt < 6; nt++) {
    const int gnt = nHalf * 6 + nt;
    const int mat = gnt >> 2;                   // 0=q 1=k 2=v (wave-uniform)
    const int col = (gnt & 3) * 16 + l16;
    if (mat <= 1) {
#pragma unroll
      for (int r = 0; r < 4; r++) {
        const float val = acc[nt][r];
        const int trow = M0 + w * 16 + quad * 4 + r;
        if (mat == 0) q [(size_t)trow * HS + col] = f2bf(val * 0.125f);
        else          kO[(size_t)trow * HS + col] = f2bf(val);
      }
    }
  }
  __syncthreads();                              // pool reads done; reuse as vls
  if (nHalf == 1) {                             // v via wave-private transpose
    float* vls = (float*)&pool[0][0] + w * 1024;   // [16][64] fp32 per wave
#pragma unroll
    for (int nt = 2; nt < 6; nt++) {            // gnt 8..11 = v cols 0..63
      const int col = ((nHalf * 6 + nt) & 3) * 16 + l16;
#pragma unroll
      for (int r = 0; r < 4; r++)
        vls[(quad * 4 + r) * 64 + col] = acc[nt][r];
    }
    const int d = lane;
    short8 p0, p1;
#pragma unroll
    for (int i = 0; i < 8; i++) p0[i] = (short)f2bf(vls[i * 64 + d]);
#pragma unroll
    for (int i = 0; i < 8; i++) p1[i] = (short)f2bf(vls[(8 + i) * 64 + d]);
    ushort_t* dst = vT + ((size_t)(M0 >> 12) * HS + d) * TSEQ
                       + (M0 & (TSEQ - 1)) + w * 16;
    *(short8*)(dst)     = p0;
    *(short8*)(dst + 8) = p1;
  }
}

// ---------------- attention pass 1: partial flash attention ----------------
// grid = 128 jt x B x KSPLIT(4) = 2048 blocks, 128 thr (2 waves).
#define KP 72
__global__ __launch_bounds__(128) void attn_part(
    const ushort_t* __restrict__ q, const ushort_t* __restrict__ k,
    const ushort_t* __restrict__ vT, float* __restrict__ ML, ushort_t* __restrict__ OP)
{
  __shared__ __align__(16) ushort_t sK[64 * KP];     // [key][d]
  __shared__ __align__(16) ushort_t sV[64 * KP];     // [d][key]
  __shared__ __align__(16) ushort_t sP[2][16 * KP];  // per-wave P

  const int idx  = blockIdx.x;
  const int s    = idx & 3;
  const int b    = (idx >> 2) & 3;
  const int jt   = 127 - (idx >> 4);           // descending work order
  const int tid  = threadIdx.x;
  const int w    = tid >> 6;
  const int lane = tid & 63;
  const int l16  = lane & 15, quad = lane >> 4;
  const int R0   = jt * 32 + w * 16;

  const ushort_t* qg = q  + (size_t)b * TSEQ * HS;
  const ushort_t* kg = k  + (size_t)b * TSEQ * HS;
  const ushort_t* vg = vT + (size_t)b * HS * TSEQ;

  const short8 qf0 = *(const short8*)(qg + (R0 + l16) * HS +      quad * 8);
  const short8 qf1 = *(const short8*)(qg + (R0 + l16) * HS + 32 + quad * 8);

  f32x4 o[4];
#pragma unroll
  for (int dt = 0; dt < 4; dt++) o[dt] = (f32x4){0.f, 0.f, 0.f, 0.f};
  float mrow = -INFINITY, lrow = 0.f;          // per-lane qrow = R0 + l16

  const int nkt = jt / 2 + 1;                  // 64-key chunks incl. diagonal
  if (s < nkt) {
    {                                          // initial stage of chunk s
      const int k0 = s * 64;
      short8 kpre[4], vpre[4];
#pragma unroll
      for (int i = 0; i < 4; i++) {
        const int c = i * 128 + tid, key = c >> 3, ch = c & 7;
        kpre[i] = *(const short8*)(kg + (size_t)(k0 + key) * HS + ch * 8);
        vpre[i] = *(const short8*)(vg + (size_t)key * TSEQ + k0 + ch * 8);
      }
#pragma unroll
      for (int i = 0; i < 4; i++) {
        const int c = i * 128 + tid, key = c >> 3, ch = c & 7;
        *(short8*)(sK + key * KP + ch * 8) = kpre[i];
        *(short8*)(sV + key * KP + ch * 8) = vpre[i];
      }
      __syncthreads();
    }
    for (int kt = s; kt < nkt; kt += KSPLIT) {
      const int k0 = kt * 64;
      const int kn = kt + KSPLIT;
      short8 kpre[4], vpre[4];
      if (kn < nkt) {                          // issue BEFORE compute
        const int g0 = kn * 64;
#pragma unroll
        for (int i = 0; i < 4; i++) {
          const int c = i * 128 + tid, key = c >> 3, ch = c & 7;
          kpre[i] = *(const short8*)(kg + (size_t)(g0 + key) * HS + ch * 8);
          vpre[i] = *(const short8*)(vg + (size_t)key * TSEQ + g0 + ch * 8);
        }
      }
      // ---- S^T = K Q^T : C[key = ct*16+quad*4+r][qrow = l16] ----
      f32x4 sT[4];
#pragma unroll
      for (int ct = 0; ct < 4; ct++) {
        sT[ct] = (f32x4){0.f, 0.f, 0.f, 0.f};
        const short8 kfa = *(const short8*)(sK + (ct * 16 + l16) * KP +      quad * 8);
        const short8 kfb = *(const short8*)(sK + (ct * 16 + l16) * KP + 32 + quad * 8);
        sT[ct] = MFMA16(kfa, qf0, sT[ct]);
        sT[ct] = MFMA16(kfb, qf1, sT[ct]);
      }
      if (k0 + 63 > R0) {                      // causal mask, diagonal only
        const int qrow = R0 + l16;
#pragma unroll
        for (int ct = 0; ct < 4; ct++)
#pragma unroll
          for (int r = 0; r < 4; r++)
            sT[ct][r] = (k0 + ct * 16 + quad * 4 + r <= qrow) ? sT[ct][r] : -INFINITY;
      }
      // ---- online softmax (per-lane row; 2 cross-quad shuffles) ----
      float tm = -INFINITY;
#pragma unroll
      for (int ct = 0; ct < 4; ct++)
#pragma unroll
        for (int r = 0; r < 4; r++) tm = fmaxf(tm, sT[ct][r]);
      tm = fmaxf(tm, __shfl_xor(tm, 16));
      tm = fmaxf(tm, __shfl_xor(tm, 32));
      const float mn = fmaxf(mrow, tm);
      const float al = __expf(mrow - mn);
      mrow = mn;
      float ps = 0.f;
#pragma unroll
      for (int ct = 0; ct < 4; ct++)
#pragma unroll
        for (int r = 0; r < 4; r++) { sT[ct][r] = __expf(sT[ct][r] - mn); ps += sT[ct][r]; }
      ps += __shfl_xor(ps, 16);
      ps += __shfl_xor(ps, 32);
      lrow = lrow * al + ps;
      // ---- P -> LDS (A-layout), O rescale, PV ----
      ushort_t* Pw = &sP[w][0];
#pragma unroll
      for (int ct = 0; ct < 4; ct++) {
        ushort4 pk;
        pk.x = f2bf(sT[ct][0]); pk.y = f2bf(sT[ct][1]);
        pk.z = f2bf(sT[ct][2]); pk.w = f2bf(sT[ct][3]);
        *(ushort4*)(Pw + l16 * KP + ct * 16 + quad * 4) = pk;
      }
      float alo[4];
#pragma unroll
      for (int r = 0; r < 4; r++) alo[r] = __shfl(al, quad * 4 + r);
#pragma unroll
      for (int dt = 0; dt < 4; dt++)
#pragma unroll
        for (int r = 0; r < 4; r++) o[dt][r] *= alo[r];
      const short8 pf0 = *(const short8*)(Pw + l16 * KP +      quad * 8);
      const short8 pf1 = *(const short8*)(Pw + l16 * KP + 32 + quad * 8);
#pragma unroll
      for (int dt = 0; dt < 4; dt++) {
        const short8 vfa = *(const short8*)(sV + (dt * 16 + l16) * KP +      quad * 8);
        const short8 vfb = *(const short8*)(sV + (dt * 16 + l16) * KP + 32 + quad * 8);
        o[dt] = MFMA16(pf0, vfa, o[dt]);
        o[dt] = MFMA16(pf1, vfb, o[dt]);
      }
      if (kn < nkt) {                          // rotate staged tile
        __syncthreads();                       // all reads of current tile done
#pragma unroll
        for (int i = 0; i < 4; i++) {
          const int c = i * 128 + tid, key = c >> 3, ch = c & 7;
          *(short8*)(sK + key * KP + ch * 8) = kpre[i];
          *(short8*)(sV + key * KP + ch * 8) = vpre[i];
        }
        __syncthreads();                       // new tile visible
      }
    }
  }

  // ---- write partials: ML fp32 [B][KSPLIT][T][2], OP bf16 [B][KSPLIT][T][64] ----
  const size_t base = ((size_t)(b * KSPLIT + s) * TSEQ);
  if (quad == 0) {
    ML[(base + R0 + l16) * 2 + 0] = mrow;
    ML[(base + R0 + l16) * 2 + 1] = lrow;
  }
#pragma unroll
  for (int dt = 0; dt < 4; dt++)
#pragma unroll
    for (int r = 0; r < 4; r++)
      OP[(base + R0 + quad * 4 + r) * HS + dt * 16 + l16] = f2bf(o[dt][r]);
}

// ---------------- attention pass 2: merge the KSPLIT partials ----------------
__global__ __launch_bounds__(256) void attn_merge(
    const float* __restrict__ ML, const ushort_t* __restrict__ OP,
    float* __restrict__ out)
{
  const int row = blockIdx.x * 16 + (threadIdx.x >> 4);   // 0..16383
  const int b   = row >> 12, t = row & (TSEQ - 1);
  const int d0  = (threadIdx.x & 15) * 4;
  float m[KSPLIT], l[KSPLIT];
  float M = -INFINITY;
#pragma unroll
  for (int ss = 0; ss < KSPLIT; ss++) {
    const size_t i = ((size_t)(b * KSPLIT + ss) * TSEQ + t);
    m[ss] = ML[i * 2]; l[ss] = ML[i * 2 + 1];
    M = fmaxf(M, m[ss]);
  }
  float den = 0.f;
  float4 num = make_float4(0.f, 0.f, 0.f, 0.f);
#pragma unroll
  for (int ss = 0; ss < KSPLIT; ss++) {
    const float a = __expf(m[ss] - M);          // zero-trip split: weight 0
    den += l[ss] * a;
    const size_t i = ((size_t)(b * KSPLIT + ss) * TSEQ + t);
    const ushort4 u = *(const ushort4*)(OP + i * HS + d0);
    num.x += a * bf2f(u.x); num.y += a * bf2f(u.y);
    num.z += a * bf2f(u.z); num.w += a * bf2f(u.w);
  }
  const float inv = 1.f / den;
  *(float4*)(out + (size_t)row * HS + d0) =
      make_float4(num.x * inv, num.y * inv, num.z * inv, num.w * inv);
}

extern "C" void kernel_launch(void* const* d_in, const int* in_sizes, int n_in,
                              void* d_out, int out_size, void* d_ws, size_t ws_size,
                              hipStream_t stream) {
  const float* x  = (const float*)d_in[0];
  const float* Wq = (const float*)d_in[1];
  const float* Wk = (const float*)d_in[2];
  const float* Wv = (const float*)d_in[3];
  float* out = (float*)d_out;

  // ws: Wt 288K | q 2M | k 2M | vT 2M | ML 512K | OP 8M | xb 24M @16M
  char* ws = (char*)d_ws;
  ushort_t* Wt = (ushort_t*)ws;
  ushort_t* qb = (ushort_t*)(ws + 294912);
  ushort_t* kb = (ushort_t*)(ws + 294912 + 2097152);
  ushort_t* vb = (ushort_t*)(ws + 294912 + 2 * 2097152);
  float*    ml = (float*)   (ws + 294912 + 3 * 2097152);
  ushort_t* op = (ushort_t*)(ws + 294912 + 3 * 2097152 + 524288);
  ushort_t* xbuf = (ushort_t*)(ws + 16777216);

  wprep<<<36, 256, 0, stream>>>(Wq, Wk, Wv, Wt);
  xcast<<<1024, 256, 0, stream>>>(x, xbuf);
  qkv_mfma<<<512, 256, 0, stream>>>(xbuf, Wt, qb, kb, vb);
  attn_part<<<128 * NBATCH * KSPLIT, 128, 0, stream>>>(qb, kb, vb, ml, op);
  attn_merge<<<1024, 256, 0, stream>>>(ml, op, out);
}